// Round 1
// baseline (741.676 us; speedup 1.0000x reference)
//
#include <hip/hip_runtime.h>

// FullyConnectedTensorProduct, B=2^20 rows of 32 f32 each side.
//   s1=x1[0:8], v1=x1[8:32] as (8,3); same for x2.
//   out0[w]   = sum_uv s1[u]s2[v]W0[uvw] + (1/sqrt3) sum_uv (v1[u].v2[v]) W1[uvw]
//   out1[w,k] = sum_uv s1[u]v2[v,k]W2[uvw] + sum_uv v1[u,k]s2[v]W3[uvw]
//
// v4: register-pressure restructure. v3 demanded ~115 live VGPRs (X1+X2 fully
// resident + 40 accum floats) but got 80 -> scratch spills + rematerialization
// (invisible in FETCH/WRITE, inflates VALUBusy), occupancy 31%. Now:
//   Phase 1: out0 only (s1,v1 resident; v2 streamed as 2x aligned float4-triples,
//            INV3 folded into the stream; W1 merged into acc0) -> store out0 early.
//   Phase 2: W3 using still-resident V1 + s2.
//   Phase 3: W2 with s1 + re-streamed v2 (L2/L3-hot; asm memory fence stops GVN
//            from CSE-ing the reload into a 24-reg live range).
// Peak live ~76 VGPRs -> __launch_bounds__(256,6) holds 6 waves/SIMD, no spills.
// Nontemporal out stores keep L3 for the x1/x2 re-reads.

typedef float v2f __attribute__((ext_vector_type(2)));
typedef float v4f __attribute__((ext_vector_type(4)));

constexpr int TPB = 256;

__global__ __launch_bounds__(TPB, 6) void tp_kernel(
    const float* __restrict__ x1,
    const float* __restrict__ x2,
    const float* __restrict__ wg,
    float* __restrict__ out,
    int batch)
{
    const float INV3  = 0.57735026918962576f;   // 1/sqrt(3)
    const float ALPHA = 0.088388347648318447f;  // 1/sqrt(128)

    int b = blockIdx.x * TPB + threadIdx.x;
    if (b >= batch) return;

    const float* r1 = x1 + (size_t)b * 32;
    const float* r2 = x2 + (size_t)b * 32;
    float*       ro = out + (size_t)b * 32;

    // Resident across phases: s1 (8), s2 (8), V1 (24). v2 is streamed.
    float s1[8], s2[8], V1[24];
    {
        const v4f* p1 = (const v4f*)r1;
        const v4f* p2 = (const v4f*)r2;
        #pragma unroll
        for (int j = 0; j < 2; ++j) {
            v4f t1 = p1[j], t2 = p2[j];
            #pragma unroll
            for (int i = 0; i < 4; ++i) { s1[4*j+i] = t1[i]; s2[4*j+i] = t2[i]; }
        }
        #pragma unroll
        for (int j = 0; j < 6; ++j) {
            v4f t = p1[2+j];
            #pragma unroll
            for (int i = 0; i < 4; ++i) V1[4*j+i] = t[i];
        }
    }

    // ---- Phase 1: out0 = sum_uv [ s1*s2*W0 + (INV3 * v1.v2)*W1 ] ----
    // v-outer in two halves; each half streams 12 floats of v2 (three aligned
    // float4s), pre-scaled by INV3 so W1 merges into the same accumulator.
    v2f acc0[4];
    #pragma unroll
    for (int j = 0; j < 4; ++j) acc0[j] = (v2f){0.f, 0.f};

    #pragma unroll
    for (int h = 0; h < 2; ++h) {
        float C[12];
        {
            const v4f* pv = (const v4f*)(r2 + 8 + 12*h);
            #pragma unroll
            for (int j = 0; j < 3; ++j) {
                v4f t = pv[j];
                #pragma unroll
                for (int i = 0; i < 4; ++i) C[4*j+i] = t[i] * INV3;
            }
        }
        #pragma unroll
        for (int vv = 0; vv < 4; ++vv) {
            const int v = 4*h + vv;
            float s2v = s2[v];
            float c0 = C[3*vv+0], c1 = C[3*vv+1], c2 = C[3*vv+2];
            #pragma unroll
            for (int u = 0; u < 8; ++u) {
                float p = s1[u] * s2v;
                float d = V1[3*u+0]*c0 + V1[3*u+1]*c1 + V1[3*u+2]*c2;
                v2f pp = {p, p}, dd = {d, d};
                const v2f* w0 = (const v2f*)(wg +        u*64 + v*8);  // W0[u][v][:]
                const v2f* w1 = (const v2f*)(wg + 512 +  u*64 + v*8);  // W1
                #pragma unroll
                for (int j = 0; j < 4; ++j) {
                    acc0[j] = __builtin_elementwise_fma(pp, w0[j], acc0[j]);
                    acc0[j] = __builtin_elementwise_fma(dd, w1[j], acc0[j]);
                }
            }
        }
    }

    // Store out0 immediately: acc0 dies here, freeing 8 VGPRs for phase 2/3.
    {
        v4f o0, o1;
        o0[0] = ALPHA * acc0[0].x; o0[1] = ALPHA * acc0[0].y;
        o0[2] = ALPHA * acc0[1].x; o0[3] = ALPHA * acc0[1].y;
        o1[0] = ALPHA * acc0[2].x; o1[1] = ALPHA * acc0[2].y;
        o1[2] = ALPHA * acc0[3].x; o1[3] = ALPHA * acc0[3].y;
        __builtin_nontemporal_store(o0, (v4f*)ro);
        __builtin_nontemporal_store(o1, (v4f*)ro + 1);
    }

    // Compiler-only fence: prevents GVN from CSE-ing phase-3's v2 reloads with
    // phase-1's loads (which would pin 24 extra regs across phase 2 -> spills).
    asm volatile("" ::: "memory");

    // out1 accumulators: a01[t] = out1[t][k0,k1], a2[t] = out1[t][2]
    v2f a01[8]; float a2[8];
    #pragma unroll
    for (int t = 0; t < 8; ++t) { a01[t] = (v2f){0.f, 0.f}; a2[t] = 0.f; }

    // ---- Phase 2: W3 (u-outer). Uses still-resident V1 and s2. ----
    #pragma unroll
    for (int u = 0; u < 8; ++u) {
        v2f f[4];
        #pragma unroll
        for (int j = 0; j < 4; ++j) f[j] = (v2f){0.f, 0.f};
        #pragma unroll
        for (int v = 0; v < 8; ++v) {
            float sv = s2[v];
            v2f ss = {sv, sv};
            const v2f* w3 = (const v2f*)(wg + 1536 + u*64 + v*8);  // W3
            #pragma unroll
            for (int j = 0; j < 4; ++j)
                f[j] = __builtin_elementwise_fma(ss, w3[j], f[j]);
        }
        float c0 = V1[3*u+0], c1 = V1[3*u+1], c2 = V1[3*u+2];
        v2f cc01 = {c0, c1};
        #pragma unroll
        for (int j = 0; j < 4; ++j) {
            float f0 = f[j].x, f1 = f[j].y;
            v2f ff0 = {f0, f0}, ff1 = {f1, f1};
            a01[2*j]   = __builtin_elementwise_fma(cc01, ff0, a01[2*j]);
            a01[2*j+1] = __builtin_elementwise_fma(cc01, ff1, a01[2*j+1]);
            a2[2*j]   += c2 * f0;
            a2[2*j+1] += c2 * f1;
        }
    }

    // ---- Phase 3: W2 (v-outer). s1 + re-streamed raw v2 halves (cache-hot). ----
    #pragma unroll
    for (int h = 0; h < 2; ++h) {
        float C[12];
        {
            const v4f* pv = (const v4f*)(r2 + 8 + 12*h);
            #pragma unroll
            for (int j = 0; j < 3; ++j) {
                v4f t = pv[j];
                #pragma unroll
                for (int i = 0; i < 4; ++i) C[4*j+i] = t[i];
            }
        }
        #pragma unroll
        for (int vv = 0; vv < 4; ++vv) {
            const int v = 4*h + vv;
            v2f e[4];
            #pragma unroll
            for (int j = 0; j < 4; ++j) e[j] = (v2f){0.f, 0.f};
            #pragma unroll
            for (int u = 0; u < 8; ++u) {
                v2f ss = {s1[u], s1[u]};
                const v2f* w2 = (const v2f*)(wg + 1024 + u*64 + v*8);  // W2
                #pragma unroll
                for (int j = 0; j < 4; ++j)
                    e[j] = __builtin_elementwise_fma(ss, w2[j], e[j]);
            }
            float c0 = C[3*vv+0], c1 = C[3*vv+1], c2 = C[3*vv+2];
            v2f cc01 = {c0, c1};
            #pragma unroll
            for (int j = 0; j < 4; ++j) {
                float e0 = e[j].x, e1 = e[j].y;
                v2f ee0 = {e0, e0}, ee1 = {e1, e1};
                a01[2*j]   = __builtin_elementwise_fma(cc01, ee0, a01[2*j]);
                a01[2*j+1] = __builtin_elementwise_fma(cc01, ee1, a01[2*j+1]);
                a2[2*j]   += c2 * e0;
                a2[2*j+1] += c2 * e1;
            }
        }
    }

    // ---- Epilogue: scale + pack + nontemporal vector store of out1 ----
    float O[24];
    #pragma unroll
    for (int t = 0; t < 8; ++t) {
        O[3*t+0] = ALPHA * a01[t].x;
        O[3*t+1] = ALPHA * a01[t].y;
        O[3*t+2] = ALPHA * a2[t];
    }
    #pragma unroll
    for (int j = 0; j < 6; ++j) {
        v4f t;
        t[0] = O[4*j+0]; t[1] = O[4*j+1]; t[2] = O[4*j+2]; t[3] = O[4*j+3];
        __builtin_nontemporal_store(t, (v4f*)(ro + 8) + j);
    }
}

extern "C" void kernel_launch(void* const* d_in, const int* in_sizes, int n_in,
                              void* d_out, int out_size, void* d_ws, size_t ws_size,
                              hipStream_t stream) {
    const float* x1 = (const float*)d_in[0];
    const float* x2 = (const float*)d_in[1];
    const float* wg = (const float*)d_in[2];
    float* out = (float*)d_out;

    int batch = in_sizes[0] / 32;
    dim3 grid((batch + TPB - 1) / TPB), block(TPB);
    hipLaunchKernelGGL(tp_kernel, grid, block, 0, stream, x1, x2, wg, out, batch);
}

// Round 2
// 621.752 us; speedup vs baseline: 1.1929x; 1.1929x over previous
//
#include <hip/hip_runtime.h>

// FullyConnectedTensorProduct, B=2^20 rows of 32 f32 each side.
//   s1=x1[0:8], v1=x1[8:32] as (8,3); same for x2.
//   out0[w]   = sum_uv s1[u]s2[v]W0[uvw] + (1/sqrt3) sum_uv (v1[u].v2[v]) W1[uvw]
//   out1[w,k] = sum_uv s1[u]v2[v,k]W2[uvw] + sum_uv v1[u,k]s2[v]W3[uvw]
//
// v5: recovery from v4's spill catastrophe. v4's launch_bounds(256,6) capped
// VGPRs at ~84, just below ~90+ peak-live -> LLVM spilled the arrays wholesale
// to scratch (VGPR=40, hbm_bytes 269MB->1.62GB, VALUBusy 14%). Keep the v4
// phase-split (it reduced true VALU time 112us->81us) but:
//   - __launch_bounds__(256,4): VGPR cap 128 >> ~95 peak demand. No spill.
//   - V2 kept resident (24 regs, headroom exists) instead of re-streamed;
//     no asm fence needed.
//   - acc0b restored (separate W1 accumulator, INV3 merged in epilogue):
//     8 regs buys back 64 per-thread v_mul.
// Phase 1: out0 (W0+W1) -> store early, acc dies. Phase 2: W3. Phase 3: W2.
// Weights are wave-uniform -> s_load_dwordx8 broadcasts, no vector-mem cost.
// Nontemporal out stores keep L3 for the 256MB of x1/x2 re-reads.

typedef float v2f __attribute__((ext_vector_type(2)));
typedef float v4f __attribute__((ext_vector_type(4)));

constexpr int TPB = 256;

__global__ __launch_bounds__(TPB, 4) void tp_kernel(
    const float* __restrict__ x1,
    const float* __restrict__ x2,
    const float* __restrict__ wg,
    float* __restrict__ out,
    int batch)
{
    const float INV3  = 0.57735026918962576f;   // 1/sqrt(3)
    const float ALPHA = 0.088388347648318447f;  // 1/sqrt(128)

    int b = blockIdx.x * TPB + threadIdx.x;
    if (b >= batch) return;

    const float* r1 = x1 + (size_t)b * 32;
    const float* r2 = x2 + (size_t)b * 32;
    float*       ro = out + (size_t)b * 32;

    // Full inputs resident: s1(8) V1(24) s2(8) V2(24) = 64 VGPRs.
    float s1[8], s2[8], V1[24], V2[24];
    {
        const v4f* p1 = (const v4f*)r1;
        const v4f* p2 = (const v4f*)r2;
        #pragma unroll
        for (int j = 0; j < 2; ++j) {
            v4f t1 = p1[j], t2 = p2[j];
            #pragma unroll
            for (int i = 0; i < 4; ++i) { s1[4*j+i] = t1[i]; s2[4*j+i] = t2[i]; }
        }
        #pragma unroll
        for (int j = 0; j < 6; ++j) {
            v4f t1 = p1[2+j], t2 = p2[2+j];
            #pragma unroll
            for (int i = 0; i < 4; ++i) { V1[4*j+i] = t1[i]; V2[4*j+i] = t2[i]; }
        }
    }

    // ---- Phase 1: out0 = ALPHA * (sum s1s2 W0  +  INV3 * sum (v1.v2) W1) ----
    v2f acc0[4], acc0b[4];
    #pragma unroll
    for (int j = 0; j < 4; ++j) { acc0[j] = (v2f){0.f,0.f}; acc0b[j] = (v2f){0.f,0.f}; }

    #pragma unroll
    for (int v = 0; v < 8; ++v) {
        float s2v = s2[v];
        float c0 = V2[3*v+0], c1 = V2[3*v+1], c2 = V2[3*v+2];
        #pragma unroll
        for (int u = 0; u < 8; ++u) {
            float p = s1[u] * s2v;
            float d = V1[3*u+0]*c0 + V1[3*u+1]*c1 + V1[3*u+2]*c2;
            v2f pp = {p, p}, dd = {d, d};
            const v2f* w0 = (const v2f*)(wg +        u*64 + v*8);  // W0[u][v][:]
            const v2f* w1 = (const v2f*)(wg + 512 +  u*64 + v*8);  // W1
            #pragma unroll
            for (int j = 0; j < 4; ++j) {
                acc0[j]  = __builtin_elementwise_fma(pp, w0[j], acc0[j]);
                acc0b[j] = __builtin_elementwise_fma(dd, w1[j], acc0b[j]);
            }
        }
    }

    // Store out0 immediately: acc0/acc0b die here (16 VGPRs freed).
    {
        v4f o0, o1;
        o0[0] = ALPHA * (acc0[0].x + INV3 * acc0b[0].x);
        o0[1] = ALPHA * (acc0[0].y + INV3 * acc0b[0].y);
        o0[2] = ALPHA * (acc0[1].x + INV3 * acc0b[1].x);
        o0[3] = ALPHA * (acc0[1].y + INV3 * acc0b[1].y);
        o1[0] = ALPHA * (acc0[2].x + INV3 * acc0b[2].x);
        o1[1] = ALPHA * (acc0[2].y + INV3 * acc0b[2].y);
        o1[2] = ALPHA * (acc0[3].x + INV3 * acc0b[3].x);
        o1[3] = ALPHA * (acc0[3].y + INV3 * acc0b[3].y);
        __builtin_nontemporal_store(o0, (v4f*)ro);
        __builtin_nontemporal_store(o1, (v4f*)ro + 1);
    }

    // out1 accumulators: a01[t] = out1[t][k0,k1], a2[t] = out1[t][2]
    v2f a01[8]; float a2[8];
    #pragma unroll
    for (int t = 0; t < 8; ++t) { a01[t] = (v2f){0.f, 0.f}; a2[t] = 0.f; }

    // ---- Phase 2: W3 (u-outer): f_w = sum_v s2[v] W3[uvw]; out1 += v1[u,k]*f_w ----
    #pragma unroll
    for (int u = 0; u < 8; ++u) {
        v2f f[4];
        #pragma unroll
        for (int j = 0; j < 4; ++j) f[j] = (v2f){0.f, 0.f};
        #pragma unroll
        for (int v = 0; v < 8; ++v) {
            float sv = s2[v];
            v2f ss = {sv, sv};
            const v2f* w3 = (const v2f*)(wg + 1536 + u*64 + v*8);  // W3
            #pragma unroll
            for (int j = 0; j < 4; ++j)
                f[j] = __builtin_elementwise_fma(ss, w3[j], f[j]);
        }
        float c0 = V1[3*u+0], c1 = V1[3*u+1], c2 = V1[3*u+2];
        v2f cc01 = {c0, c1};
        #pragma unroll
        for (int j = 0; j < 4; ++j) {
            float f0 = f[j].x, f1 = f[j].y;
            v2f ff0 = {f0, f0}, ff1 = {f1, f1};
            a01[2*j]   = __builtin_elementwise_fma(cc01, ff0, a01[2*j]);
            a01[2*j+1] = __builtin_elementwise_fma(cc01, ff1, a01[2*j+1]);
            a2[2*j]   += c2 * f0;
            a2[2*j+1] += c2 * f1;
        }
    }

    // ---- Phase 3: W2 (v-outer): e_w = sum_u s1[u] W2[uvw]; out1 += v2[v,k]*e_w ----
    #pragma unroll
    for (int v = 0; v < 8; ++v) {
        v2f e[4];
        #pragma unroll
        for (int j = 0; j < 4; ++j) e[j] = (v2f){0.f, 0.f};
        #pragma unroll
        for (int u = 0; u < 8; ++u) {
            v2f ss = {s1[u], s1[u]};
            const v2f* w2 = (const v2f*)(wg + 1024 + u*64 + v*8);  // W2
            #pragma unroll
            for (int j = 0; j < 4; ++j)
                e[j] = __builtin_elementwise_fma(ss, w2[j], e[j]);
        }
        float c0 = V2[3*v+0], c1 = V2[3*v+1], c2 = V2[3*v+2];
        v2f cc01 = {c0, c1};
        #pragma unroll
        for (int j = 0; j < 4; ++j) {
            float e0 = e[j].x, e1 = e[j].y;
            v2f ee0 = {e0, e0}, ee1 = {e1, e1};
            a01[2*j]   = __builtin_elementwise_fma(cc01, ee0, a01[2*j]);
            a01[2*j+1] = __builtin_elementwise_fma(cc01, ee1, a01[2*j+1]);
            a2[2*j]   += c2 * e0;
            a2[2*j+1] += c2 * e1;
        }
    }

    // ---- Epilogue: scale + pack + nontemporal vector store of out1 ----
    float O[24];
    #pragma unroll
    for (int t = 0; t < 8; ++t) {
        O[3*t+0] = ALPHA * a01[t].x;
        O[3*t+1] = ALPHA * a01[t].y;
        O[3*t+2] = ALPHA * a2[t];
    }
    #pragma unroll
    for (int j = 0; j < 6; ++j) {
        v4f t;
        t[0] = O[4*j+0]; t[1] = O[4*j+1]; t[2] = O[4*j+2]; t[3] = O[4*j+3];
        __builtin_nontemporal_store(t, (v4f*)(ro + 8) + j);
    }
}

extern "C" void kernel_launch(void* const* d_in, const int* in_sizes, int n_in,
                              void* d_out, int out_size, void* d_ws, size_t ws_size,
                              hipStream_t stream) {
    const float* x1 = (const float*)d_in[0];
    const float* x2 = (const float*)d_in[1];
    const float* wg = (const float*)d_in[2];
    float* out = (float*)d_out;

    int batch = in_sizes[0] / 32;
    dim3 grid((batch + TPB - 1) / TPB), block(TPB);
    hipLaunchKernelGGL(tp_kernel, grid, block, 0, stream, x1, x2, wg, out, batch);
}